// Round 14
// baseline (82.905 us; speedup 1.0000x reference)
//
#include <hip/hip_runtime.h>
#include <hip/hip_bf16.h>

// ODELSTMCell: B=16384, I=256, H=256, OH=64, 8 fixed dopri5 steps.
// prep_kernel : wsB=[W_ih|W_hh] bf16; Wc=W1@W2 bf16; u=b2@W1^T f32;
//               w1B=W1 bf16; w2B=W2 bf16.
// lstm_kernel : R13-verified m97-shaped GEMM (unchanged, 41.5us).
// ode_kernel  : 2-WAVE split of the zero-exchange G-space dopri5:
//   wave w owns feature-tiles {2w,2w+1}; per round each wave does 4 MFMA +
//   8 tanh (half of R10) and exchanges its half-fragment via 16B/lane LDS
//   (double-buffered, one __syncthreads per round). 1024 blocks x 128 thr
//   = 2048 waves = 2 waves/SIMD -> latency hiding at halved issue.

#define B_N 16384
#define H_N 256

typedef __attribute__((ext_vector_type(8))) short short8;          // 8 x bf16
typedef __attribute__((ext_vector_type(4))) unsigned short u16x4;  // 4 x bf16
typedef __attribute__((ext_vector_type(4))) float f32x4;

__device__ __forceinline__ unsigned short f2bf_s(float x) {
  __hip_bfloat16 h = __float2bfloat16(x);
  return *reinterpret_cast<unsigned short*>(&h);
}

__device__ __forceinline__ short8 pack8f(const float* p) {
  const f32x4 a = *(const f32x4*)p;
  const f32x4 b = *(const f32x4*)(p + 4);
  short8 r;
  r[0] = (short)f2bf_s(a[0]); r[1] = (short)f2bf_s(a[1]);
  r[2] = (short)f2bf_s(a[2]); r[3] = (short)f2bf_s(a[3]);
  r[4] = (short)f2bf_s(b[0]); r[5] = (short)f2bf_s(b[1]);
  r[6] = (short)f2bf_s(b[2]); r[7] = (short)f2bf_s(b[3]);
  return r;
}

__device__ __forceinline__ short8 pack8v(f32x4 a, f32x4 b) {
  short8 r;
  r[0] = (short)f2bf_s(a[0]); r[1] = (short)f2bf_s(a[1]);
  r[2] = (short)f2bf_s(a[2]); r[3] = (short)f2bf_s(a[3]);
  r[4] = (short)f2bf_s(b[0]); r[5] = (short)f2bf_s(b[1]);
  r[6] = (short)f2bf_s(b[2]); r[7] = (short)f2bf_s(b[3]);
  return r;
}

__device__ __forceinline__ float fast_sigmoid(float x) {
  return __builtin_amdgcn_rcpf(1.f + __expf(-x));
}
// clamp-free: e^inf -> rcp 0 -> 1; e^-inf -> 0 -> -1  (exact limits)
__device__ __forceinline__ float fast_tanh(float x) {
  float e = __expf(2.f * x);
  return 1.f - 2.f * __builtin_amdgcn_rcpf(e + 1.f);
}

__device__ __forceinline__ void gl_lds16(const void* g, void* l) {
  __builtin_amdgcn_global_load_lds(
      (const __attribute__((address_space(1))) void*)g,
      (__attribute__((address_space(3))) void*)l, 16, 0, 0);
}

// ---------------------------------------------------------------------------
// prep: [0,256) wsB; [256,272) Wc=W1@W2; 272 u=b2@W1^T; [273,281) w1B; [281,289) w2B
// ---------------------------------------------------------------------------
__global__ __launch_bounds__(256) void prep_kernel(
    const float* __restrict__ Wih, const float* __restrict__ Whh,
    const float* __restrict__ W1, const float* __restrict__ W2,
    const float* __restrict__ b2,
    unsigned short* __restrict__ wsB, unsigned short* __restrict__ wcB,
    float* __restrict__ uF, unsigned short* __restrict__ w1B,
    unsigned short* __restrict__ w2B) {
  const int bx = blockIdx.x;
  if (bx < 256) {
    int idx = bx * 256 + threadIdx.x;
    int n = idx >> 6, c = idx & 63, k = c * 8;
    const float* src = (k < 256) ? (Wih + (size_t)n * 256 + k)
                                 : (Whh + (size_t)n * 256 + (k - 256));
    *(short8*)(wsB + (size_t)n * 512 + k) = pack8f(src);
  } else if (bx < 272) {
    int idx = (bx - 256) * 256 + threadIdx.x;  // [0,4096)
    int f = idx >> 6, o = idx & 63;
    float a0 = 0.f, a1 = 0.f, a2 = 0.f, a3 = 0.f;
    for (int h = 0; h < 256; h += 4) {
      a0 = fmaf(W1[f * 256 + h],     W2[h * 64 + o],        a0);
      a1 = fmaf(W1[f * 256 + h + 1], W2[(h + 1) * 64 + o],  a1);
      a2 = fmaf(W1[f * 256 + h + 2], W2[(h + 2) * 64 + o],  a2);
      a3 = fmaf(W1[f * 256 + h + 3], W2[(h + 3) * 64 + o],  a3);
    }
    wcB[f * 64 + o] = f2bf_s((a0 + a1) + (a2 + a3));
  } else if (bx == 272) {
    int f = threadIdx.x;
    if (f < 64) {
      float a0 = 0.f, a1 = 0.f, a2 = 0.f, a3 = 0.f;
      for (int h = 0; h < 256; h += 4) {
        a0 = fmaf(W1[f * 256 + h],     b2[h],     a0);
        a1 = fmaf(W1[f * 256 + h + 1], b2[h + 1], a1);
        a2 = fmaf(W1[f * 256 + h + 2], b2[h + 2], a2);
        a3 = fmaf(W1[f * 256 + h + 3], b2[h + 3], a3);
      }
      uF[f] = (a0 + a1) + (a2 + a3);
    }
  } else if (bx < 281) {
    int idx = (bx - 273) * 256 + threadIdx.x;  // [0,2048)
    *(short8*)(w1B + (size_t)idx * 8) = pack8f(W1 + (size_t)idx * 8);
  } else {
    int idx = (bx - 281) * 256 + threadIdx.x;  // [0,2048)
    *(short8*)(w2B + (size_t)idx * 8) = pack8f(W2 + (size_t)idx * 8);
  }
}

// ---------------------------------------------------------------------------
// lstm (R13-verified, unchanged): grid (128,4), 512 thr, BK=64 dbuf LDS.
// ---------------------------------------------------------------------------
__global__ __launch_bounds__(512, 4) void lstm_kernel(
    const float* __restrict__ x, const float* __restrict__ hp,
    const float* __restrict__ cp, const unsigned short* __restrict__ wsB,
    const float* __restrict__ bih, const float* __restrict__ bhh,
    float* __restrict__ out) {
  __shared__ __align__(16) unsigned short Abf[2][128 * 32];  // 8KB x2
  __shared__ __align__(16) unsigned short Bbf[2][256 * 32];  // 16KB x2

  const int tid = threadIdx.x;
  const int lane = tid & 63;
  const int wv = tid >> 6;
  const int rg = wv >> 2;
  const int cg = wv & 3;
  const int s = lane & 15, q = lane >> 4;
  const int mb = blockIdx.x * 128;
  const int hb = blockIdx.y;

  f32x4 acc[4][4];
#pragma unroll
  for (int mt = 0; mt < 4; ++mt)
#pragma unroll
    for (int g = 0; g < 4; ++g) acc[mt][g] = (f32x4){0.f, 0.f, 0.f, 0.f};

  const int rA = tid >> 2, q4 = tid & 3;
  const int physA = q4 ^ ((rA >> 1) & 3);

  for (int kt = 0; kt < 8; ++kt) {
    const float* srcA = (kt < 4) ? x : hp;
    const int kl = (kt * 64) & 255;

#pragma unroll
    for (int u = 0; u < 2; ++u)
#pragma unroll
      for (int j = 0; j < 2; ++j) {
        int c = wv * 32 + j * 16 + (lane >> 2);
        int lc = (lane & 3) ^ ((c >> 1) & 3);
        int n = (c >> 6) * 256 + hb * 64 + (c & 63);
        gl_lds16(wsB + (size_t)n * 512 + kt * 64 + u * 32 + lc * 8,
                 (char*)Bbf[u] + (wv * 32 + j * 16) * 64);
      }
#pragma unroll
    for (int u = 0; u < 2; ++u) {
      const float* ap = srcA + (size_t)(mb + rA) * 256 + kl + u * 32 + q4 * 8;
      f32x4 v0 = *(const f32x4*)ap;
      f32x4 v1 = *(const f32x4*)(ap + 4);
      *(short8*)((char*)Abf[u] + rA * 64 + physA * 16) = pack8v(v0, v1);
    }
    __syncthreads();

#pragma unroll
    for (int u = 0; u < 2; ++u) {
      short8 af[4];
#pragma unroll
      for (int mt = 0; mt < 4; ++mt) {
        int r = rg * 64 + mt * 16 + s;
        af[mt] = *(const short8*)((char*)Abf[u] + r * 64 +
                                  ((q ^ ((r >> 1) & 3)) << 4));
      }
#pragma unroll
      for (int g = 0; g < 4; ++g) {
        int c = (g * 4 + cg) * 16 + s;
        short8 bfr = *(const short8*)((char*)Bbf[u] + c * 64 +
                                      ((q ^ ((c >> 1) & 3)) << 4));
#pragma unroll
        for (int mt = 0; mt < 4; ++mt)
          acc[mt][g] =
              __builtin_amdgcn_mfma_f32_16x16x32_bf16(af[mt], bfr, acc[mt][g], 0, 0, 0);
      }
    }
    __syncthreads();
  }

#pragma unroll
  for (int mt = 0; mt < 4; ++mt)
#pragma unroll
    for (int r = 0; r < 4; ++r) {
      int sample = mb + rg * 64 + mt * 16 + q * 4 + r;
      int h = hb * 64 + cg * 16 + s;
      float gi = acc[mt][0][r] + bih[h] + bhh[h];
      float gf = acc[mt][1][r] + bih[256 + h] + bhh[256 + h];
      float gg = acc[mt][2][r] + bih[512 + h] + bhh[512 + h];
      float go = acc[mt][3][r] + bih[768 + h] + bhh[768 + h];
      float iv = fast_sigmoid(gi), fv = fast_sigmoid(gf);
      float gv = fast_tanh(gg), ov = fast_sigmoid(go);
      float c = fv * cp[(size_t)sample * 256 + h] + iv * gv;
      float hv = ov * fast_tanh(c);
      out[(size_t)B_N * H_N + (size_t)sample * 256 + h] = c;
      out[(size_t)sample * 256 + h] = hv;
    }
}

// ---------------------------------------------------------------------------
// ode: 2-wave zero-exchange G-space dopri5. 128 thr = 2 waves, 16 samples.
// Wave w owns tiles j=0,1 (global i=2w+j): permuted features w*32+8q+4j+r.
// Per round: pack own half-frag (16B) -> LDS -> __syncthreads -> read other
// half -> 4 MFMA -> tanh. Double-buffered exchange, 1 barrier/round.
// ---------------------------------------------------------------------------
__global__ __launch_bounds__(128) void ode_kernel(
    float* __restrict__ out, const float* __restrict__ ts,
    const unsigned short* __restrict__ wcB, const float* __restrict__ uF,
    const unsigned short* __restrict__ w1B, const unsigned short* __restrict__ w2B,
    const float* __restrict__ b1, const float* __restrict__ b2) {
  __shared__ __align__(16) unsigned short xch[2][2][16 * 4 * 8];  // 4KB

  const int tid = threadIdx.x;
  const int lane = tid & 63;
  const int w = tid >> 6;  // 0..1
  const int s = lane & 15, q = lane >> 4;
  const int bb = blockIdx.x * 16;
  const int slot = (s * 4 + q) * 8;  // ushort index of this lane's 16B

  // tile i = 2w+j:  grow = w*32 + (s>>2)*8 + j*4 + (s&3); fbase = w*32 + q*8 + j*4
  short8 wcf[2][2];
#pragma unroll
  for (int j = 0; j < 2; ++j) {
    const int gr = w * 32 + ((s >> 2) * 8) + j * 4 + (s & 3);
#pragma unroll
    for (int kt = 0; kt < 2; ++kt)
      wcf[j][kt] = *(const short8*)(wcB + (size_t)gr * 64 + kt * 32 + q * 8);
  }
  f32x4 b1v[2], u4[2];
#pragma unroll
  for (int j = 0; j < 2; ++j) {
    b1v[j] = *(const f32x4*)(b1 + w * 32 + q * 8 + j * 4);
    u4[j] = *(const f32x4*)(uF + w * 32 + q * 8 + j * 4);
  }
  const float dt = ts[bb + s] * 0.125f;

  // G0 = y0 @ W1^T (rows permuted), then fold b1 (Ghat)
  f32x4 G[2];
#pragma unroll
  for (int j = 0; j < 2; ++j) G[j] = (f32x4){0.f, 0.f, 0.f, 0.f};
#pragma unroll
  for (int kt = 0; kt < 8; ++kt) {
    short8 yf = pack8f(out + (size_t)(bb + s) * 256 + kt * 32 + q * 8);
#pragma unroll
    for (int j = 0; j < 2; ++j) {
      const int gr = w * 32 + ((s >> 2) * 8) + j * 4 + (s & 3);
      short8 w1f = *(const short8*)(w1B + (size_t)gr * 256 + kt * 32 + q * 8);
      G[j] = __builtin_amdgcn_mfma_f32_16x16x32_bf16(w1f, yf, G[j], 0, 0, 0);
    }
  }
#pragma unroll
  for (int j = 0; j < 2; ++j) G[j] += b1v[j];

  int buf = 0;
  // exchange own half, return (zf0, zf1) both halves
  auto exch = [&](const f32x4 (&zc)[2], short8& zf0, short8& zf1) {
    short8 own = pack8v(zc[0], zc[1]);
    *(short8*)(&xch[buf][w][slot]) = own;
    __syncthreads();
    short8 oth = *(const short8*)(&xch[buf][1 - w][slot]);
    zf0 = w ? oth : own;
    zf1 = w ? own : oth;
    buf ^= 1;
  };
  auto wcmm = [&](short8 zf0, short8 zf1, f32x4 (&o)[2]) {
#pragma unroll
    for (int j = 0; j < 2; ++j) {
      f32x4 a = (f32x4){0.f, 0.f, 0.f, 0.f};
      a = __builtin_amdgcn_mfma_f32_16x16x32_bf16(wcf[j][0], zf0, a, 0, 0, 0);
      a = __builtin_amdgcn_mfma_f32_16x16x32_bf16(wcf[j][1], zf1, a, 0, 0, 0);
      o[j] = a;
    }
  };
  auto stage = [&](const f32x4 (&zc)[2], float cj, f32x4 (&zo)[2]) {
    short8 zf0, zf1;
    exch(zc, zf0, zf1);
    f32x4 o[2];
    wcmm(zf0, zf1, o);
#pragma unroll
    for (int j = 0; j < 2; ++j)
#pragma unroll
      for (int r = 0; r < 4; ++r)
        zo[j][r] = fast_tanh(fmaf(dt, fmaf(cj, u4[j][r], o[j][r]), G[j][r]));
  };

  const float A31 = 3.f / 40.f, A32 = 9.f / 40.f;
  const float A41 = 44.f / 45.f, A42 = -56.f / 15.f, A43 = 32.f / 9.f;
  const float A51 = 19372.f / 6561.f, A52 = -25360.f / 2187.f,
              A53 = 64448.f / 6561.f, A54 = -212.f / 729.f;
  const float A61 = 9017.f / 3168.f, A62 = -355.f / 33.f, A63 = 46732.f / 5247.f,
              A64 = 49.f / 176.f, A65 = -5103.f / 18656.f;
  const float C1 = 35.f / 384.f, C3 = 500.f / 1113.f, C4 = 125.f / 192.f,
              C5 = -2187.f / 6784.f, C6 = 11.f / 84.f;

  f32x4 SC[2];
#pragma unroll
  for (int j = 0; j < 2; ++j) SC[j] = (f32x4){0.f, 0.f, 0.f, 0.f};
  f32x4 z1[2], z2[2], z3[2], z4[2], z5[2], zc[2];

  for (int st = 0; st < 8; ++st) {
#pragma unroll
    for (int j = 0; j < 2; ++j)
#pragma unroll
      for (int r = 0; r < 4; ++r) z1[j][r] = fast_tanh(G[j][r]);

#pragma unroll
    for (int j = 0; j < 2; ++j) zc[j] = 0.2f * z1[j];
    stage(zc, 0.2f, z2);
#pragma unroll
    for (int j = 0; j < 2; ++j) zc[j] = A31 * z1[j] + A32 * z2[j];
    stage(zc, 0.3f, z3);
#pragma unroll
    for (int j = 0; j < 2; ++j) zc[j] = A41 * z1[j] + A42 * z2[j] + A43 * z3[j];
    stage(zc, 0.8f, z4);
#pragma unroll
    for (int j = 0; j < 2; ++j)
      zc[j] = A51 * z1[j] + A52 * z2[j] + A53 * z3[j] + A54 * z4[j];
    stage(zc, 8.f / 9.f, z5);
#pragma unroll
    for (int j = 0; j < 2; ++j)
      zc[j] = A61 * z1[j] + A62 * z2[j] + A63 * z3[j] + A64 * z4[j] + A65 * z5[j];
    // stage 6 fused: z6 transient, output-combo built in place
    {
      short8 zf0, zf1;
      exch(zc, zf0, zf1);
      f32x4 o[2];
      wcmm(zf0, zf1, o);
#pragma unroll
      for (int j = 0; j < 2; ++j)
#pragma unroll
        for (int r = 0; r < 4; ++r) {
          float z6v = fast_tanh(fmaf(dt, u4[j][r] + o[j][r], G[j][r]));
          zc[j][r] = C1 * z1[j][r] + C3 * z3[j][r] + C4 * z4[j][r] +
                     C5 * z5[j][r] + C6 * z6v;
        }
    }
    // G += dt*(u + zC@Wc^T); SC += zC
    {
      short8 zf0, zf1;
      exch(zc, zf0, zf1);
      f32x4 o6[2];
      wcmm(zf0, zf1, o6);
#pragma unroll
      for (int j = 0; j < 2; ++j) {
        SC[j] += zc[j];
#pragma unroll
        for (int r = 0; r < 4; ++r)
          G[j][r] = fmaf(dt, u4[j][r] + o6[j][r], G[j][r]);
      }
    }
  }

  // epilogue: y = y0 + dt*(8*b2 + SC@W2^T); wave w does W2 row-tiles w*8..w*8+7
  {
    short8 sf0, sf1;
    exch(SC, sf0, sf1);
#pragma unroll
    for (int ft = 0; ft < 8; ++ft) {
      const int f = w * 8 + ft;
      short8 w2a = *(const short8*)(w2B + (size_t)(f * 16 + s) * 64 + q * 8);
      short8 w2b = *(const short8*)(w2B + (size_t)(f * 16 + s) * 64 + 32 + q * 8);
      f32x4 a = (f32x4){0.f, 0.f, 0.f, 0.f};
      a = __builtin_amdgcn_mfma_f32_16x16x32_bf16(w2a, sf0, a, 0, 0, 0);
      a = __builtin_amdgcn_mfma_f32_16x16x32_bf16(w2b, sf1, a, 0, 0, 0);
      f32x4 y0 = *(const f32x4*)(out + (size_t)(bb + s) * 256 + f * 16 + q * 4);
      f32x4 b2v = *(const f32x4*)(b2 + f * 16 + q * 4);
#pragma unroll
      for (int r = 0; r < 4; ++r)
        y0[r] = fmaf(dt, fmaf(8.f, b2v[r], a[r]), y0[r]);
      *(f32x4*)(out + (size_t)(bb + s) * 256 + f * 16 + q * 4) = y0;
    }
  }
}

extern "C" void kernel_launch(void* const* d_in, const int* in_sizes, int n_in,
                              void* d_out, int out_size, void* d_ws, size_t ws_size,
                              hipStream_t stream) {
  const float* x   = (const float*)d_in[0];
  const float* hp  = (const float*)d_in[1];
  const float* cp  = (const float*)d_in[2];
  const float* ts  = (const float*)d_in[3];
  const float* Wih = (const float*)d_in[4];
  const float* Whh = (const float*)d_in[5];
  const float* bih = (const float*)d_in[6];
  const float* bhh = (const float*)d_in[7];
  const float* W1  = (const float*)d_in[8];
  const float* b1  = (const float*)d_in[9];
  const float* W2  = (const float*)d_in[10];
  const float* b2  = (const float*)d_in[11];
  float* out = (float*)d_out;

  unsigned short* wsB = (unsigned short*)d_ws;                       // 1 MB
  unsigned short* wcB = (unsigned short*)((char*)d_ws + 1048576);    // 8 KB
  float* uF = (float*)((char*)d_ws + 1048576 + 8192);                // 256 B
  unsigned short* w1B = (unsigned short*)((char*)d_ws + 1048576 + 16384);  // 32 KB
  unsigned short* w2B = (unsigned short*)((char*)d_ws + 1048576 + 49152);  // 32 KB

  prep_kernel<<<289, 256, 0, stream>>>(Wih, Whh, W1, W2, b2, wsB, wcB, uF, w1B, w2B);
  lstm_kernel<<<dim3(128, 4), 512, 0, stream>>>(x, hp, cp, wsB, bih, bhh, out);
  ode_kernel<<<1024, 128, 0, stream>>>(out, ts, wcB, uF, w1B, w2B, b1, b2);
}